// Round 13
// baseline (60.180 us; speedup 1.0000x reference)
//
#include <hip/hip_runtime.h>
#include <hip/hip_bf16.h>

#define N_TOKENS   262144
#define DIM        64
#define KCODES     512
#define OUT_ELEMS  (N_TOKENS * DIM)          // 16777216
#define LOSS_SCALE (1.25f / 16777216.0f)

typedef float  f32x4 __attribute__((ext_vector_type(4)));
typedef float  f32x8 __attribute__((ext_vector_type(8)));
typedef int    i32x4 __attribute__((ext_vector_type(4)));
typedef int    i32x2 __attribute__((ext_vector_type(2)));

// Pack 8 f32 -> 8 fp8 e4m3 bytes (j-th byte = fp8(v[j])) via v_cvt_pk_fp8_f32.
static __device__ __forceinline__ long pack_fp8x8(const f32x8 v) {
    int lo = __builtin_amdgcn_cvt_pk_fp8_f32(v[0], v[1], 0, false);
    lo     = __builtin_amdgcn_cvt_pk_fp8_f32(v[2], v[3], lo, true);
    int hi = __builtin_amdgcn_cvt_pk_fp8_f32(v[4], v[5], 0, false);
    hi     = __builtin_amdgcn_cvt_pk_fp8_f32(v[6], v[7], hi, true);
    i32x2 r = {lo, hi};
    return __builtin_bit_cast(long, r);
}

// Prep: codebook -> fp8(-256*c) in MFMA-fragment order; c2 = 128*||c||^2+256;
// zero loss slot. Fragment byte index for (code k, dim d):
//   t=k>>4, li=k&15, kk=d>>5, hi=(d>>3)&3, j=d&7 -> ((t*2+kk)*64 + hi*16+li)*8 + j
// Scale 2^7 lifts |2c|<=1/256 out of the e4m3 subnormal floor; +256 bias keeps
// distance keys strictly positive so uint compare == float compare.
__global__ void vq_prep(const float* __restrict__ cb,
                        unsigned char* __restrict__ cbf,
                        float* __restrict__ c2,
                        float* __restrict__ out_loss) {
    const int k = blockIdx.x;       // 512 blocks, one code each
    const int d = threadIdx.x;      // 64 threads (one wave)
    const float v = cb[k * DIM + d];
    float s = v * v;
    #pragma unroll
    for (int sh = 1; sh < 64; sh <<= 1) s += __shfl_xor(s, sh, 64);
    if (d == 0) c2[k] = 128.0f * s + 256.0f;

    const int t = k >> 4, li = k & 15;
    const int kk = d >> 5, hi = (d >> 3) & 3, j = d & 7;
    const int slot = (t * 2 + kk) * 64 + hi * 16 + li;
    const int p = __builtin_amdgcn_cvt_pk_fp8_f32(-256.0f * v, 0.0f, 0, false);
    cbf[slot * 8 + j] = (unsigned char)(p & 0xFF);

    if (k == 0 && d == 0) *out_loss = 0.0f;
}

// ---------------------------------------------------------------------------
// Kernel A: argmin + loss only. 1024 blocks x 512 thr (8 waves), 32 tok/wave.
// Reads z (67 MB), writes ONE u32 key per token (1 MB) + loss atomics.
// No z_q gather/write -> short epilogue, small live set, no spill pressure.
// launch_bounds(512,4): 128-VGPR cap (R3/R6/R11: tighter or absent -> spill).
// ---------------------------------------------------------------------------
__global__ __launch_bounds__(512, 4) void vq_argmin(
    const float* __restrict__ z,
    const unsigned char* __restrict__ cbf,     // fp8(-256c), fragment order
    const float* __restrict__ c2g,             // 128*||c||^2 + 256
    unsigned* __restrict__ keys,               // [N_TOKENS] out
    float* __restrict__ out_loss)
{
    __shared__ unsigned char cbs[KCODES * DIM];   // 32 KiB
    __shared__ float c2s[KCODES];                 // 2 KiB
    __shared__ int   keysl[8][32];
    __shared__ float lpart[8];

    const int tid  = threadIdx.x;
    const int wave = tid >> 6;
    const int lane = tid & 63;
    const int li   = lane & 15;
    const int hi   = lane >> 4;

    const int token0 = blockIdx.x * 256 + wave * 32;

    // z loads issue first; staging + convert overlap their latency
    const float* zb = z + (size_t)token0 * DIM + li * DIM + hi * 8;
    const f32x8 v00 = *(const f32x8*)(zb);
    const f32x8 v01 = *(const f32x8*)(zb + 32);
    const f32x8 v10 = *(const f32x8*)(zb + 16 * DIM);
    const f32x8 v11 = *(const f32x8*)(zb + 16 * DIM + 32);

    #pragma unroll
    for (int i = 0; i < 4; ++i)
        ((i32x4*)cbs)[i * 512 + tid] = ((const i32x4*)cbf)[i * 512 + tid];
    c2s[tid] = c2g[tid];   // tid < 512 == KCODES

    long af[2][2];
    float z2[2];
    {
        float zs = 0.f;
        #pragma unroll
        for (int j = 0; j < 8; ++j) zs += v00[j] * v00[j] + v01[j] * v01[j];
        af[0][0] = pack_fp8x8(v00);
        af[0][1] = pack_fp8x8(v01);
        zs += __shfl_xor(zs, 16, 64);
        zs += __shfl_xor(zs, 32, 64);
        z2[0] = zs;
    }
    {
        float zs = 0.f;
        #pragma unroll
        for (int j = 0; j < 8; ++j) zs += v10[j] * v10[j] + v11[j] * v11[j];
        af[1][0] = pack_fp8x8(v10);
        af[1][1] = pack_fp8x8(v11);
        zs += __shfl_xor(zs, 16, 64);
        zs += __shfl_xor(zs, 32, 64);
        z2[1] = zs;
    }
    __syncthreads();

    unsigned bkey[2][4];
    #pragma unroll
    for (int m = 0; m < 2; ++m)
        #pragma unroll
        for (int r = 0; r < 4; ++r) bkey[m][r] = 0xFFFFFFFFu;

    #pragma unroll 4
    for (int t = 0; t < 32; ++t) {
        const long b0 = *(const long*)&cbs[((t * 2 + 0) * 64 + lane) * 8];
        const long b1 = *(const long*)&cbs[((t * 2 + 1) * 64 + lane) * 8];
        const float cv = c2s[t * 16 + li];
        const unsigned code = (unsigned)(t * 16 + li);
        #pragma unroll
        for (int m = 0; m < 2; ++m) {
            f32x4 acc = {cv, cv, cv, cv};
            acc = __builtin_amdgcn_mfma_f32_16x16x32_fp8_fp8(af[m][0], b0, acc, 0, 0, 0);
            acc = __builtin_amdgcn_mfma_f32_16x16x32_fp8_fp8(af[m][1], b1, acc, 0, 0, 0);
            #pragma unroll
            for (int r = 0; r < 4; ++r) {
                const unsigned key = (__builtin_bit_cast(unsigned, acc[r]) & ~511u) | code;
                if (key < bkey[m][r]) bkey[m][r] = key;
            }
        }
    }

    #pragma unroll
    for (int sh = 1; sh < 16; sh <<= 1) {
        #pragma unroll
        for (int m = 0; m < 2; ++m)
            #pragma unroll
            for (int r = 0; r < 4; ++r) {
                const unsigned ok = (unsigned)__shfl_xor((int)bkey[m][r], sh, 64);
                if (ok < bkey[m][r]) bkey[m][r] = ok;
            }
    }

    if (li == 0) {
        #pragma unroll
        for (int m = 0; m < 2; ++m)
            #pragma unroll
            for (int r = 0; r < 4; ++r)
                keysl[wave][m * 16 + hi * 4 + r] = (int)bkey[m][r];
    }
    // same-wave LDS ordering via lgkmcnt; no barrier needed

    float lossp = 0.f;
    #pragma unroll
    for (int m = 0; m < 2; ++m) {
        const unsigned key = (unsigned)keysl[wave][m * 16 + li];  // row = m*16+li
        if (hi == 0) {
            const float kf = __builtin_bit_cast(float, key & ~511u);
            lossp += __builtin_fmaf(kf - 256.0f, 0.0078125f, z2[m]);  // dist~ + ||z||^2
            keys[token0 + m * 16 + li] = key;   // coalesced 16-lane store
        }
    }

    #pragma unroll
    for (int sh = 1; sh < 64; sh <<= 1) lossp += __shfl_xor(lossp, sh, 64);
    if (lane == 0) lpart[wave] = lossp;
    __syncthreads();
    if (tid == 0) {
        float s = 0.f;
        #pragma unroll
        for (int w = 0; w < 8; ++w) s += lpart[w];
        atomicAdd(out_loss, s * LOSS_SCALE);
    }
}

// ---------------------------------------------------------------------------
// Kernel B: pure gather->stream. chunk c = 32 B of one token row.
// thread: code = keys[c>>3] & 511; q = cb[code*64 + (c&7)*8]; out[c*8] = q (NT).
// 2048 blocks x 256 thr x 4 chunks; ~18 VGPR, no LDS, no barriers ->
// 32 waves/CU; gather source is the 128 KiB L2/L3-resident fp32 codebook.
// ---------------------------------------------------------------------------
__global__ __launch_bounds__(256, 4) void vq_gather(
    const float* __restrict__ cb,
    const unsigned* __restrict__ keys,
    float* __restrict__ out)
{
    const int base = blockIdx.x * 1024 + threadIdx.x;   // 4 chunks, stride 256
    #pragma unroll
    for (int i = 0; i < 4; ++i) {
        const int c = base + i * 256;
        const int token = c >> 3, part = c & 7;
        const int code = (int)(keys[token] & 511u);
        const f32x8 q = *(const f32x8*)(cb + code * DIM + part * 8);
        __builtin_nontemporal_store(q, (f32x8*)(out + (size_t)c * 8));
    }
}

extern "C" void kernel_launch(void* const* d_in, const int* in_sizes, int n_in,
                              void* d_out, int out_size, void* d_ws, size_t ws_size,
                              hipStream_t stream) {
    const float* z  = (const float*)d_in[0];
    const float* cb = (const float*)d_in[1];
    float* out = (float*)d_out;

    unsigned char* cbf  = (unsigned char*)d_ws;                      // 32 KiB
    float*         c2   = (float*)((char*)d_ws + KCODES * DIM);      // 2 KiB
    unsigned*      keys = (unsigned*)((char*)d_ws + KCODES * DIM + KCODES * 4); // 1 MiB

    vq_prep<<<KCODES, 64, 0, stream>>>(cb, cbf, c2, out + OUT_ELEMS);
    vq_argmin<<<N_TOKENS / 256, 512, 0, stream>>>(z, cbf, c2, keys, out + OUT_ELEMS);
    vq_gather<<<(N_TOKENS * 8) / 1024, 256, 0, stream>>>(cb, keys, out);
}

// Round 14
// 46.566 us; speedup vs baseline: 1.2924x; 1.2924x over previous
//
#include <hip/hip_runtime.h>
#include <hip/hip_bf16.h>

#define N_TOKENS   262144
#define DIM        64
#define KCODES     512
#define OUT_ELEMS  (N_TOKENS * DIM)          // 16777216
#define LOSS_SCALE (1.25f / 16777216.0f)

typedef float  f32x4 __attribute__((ext_vector_type(4)));
typedef float  f32x8 __attribute__((ext_vector_type(8)));
typedef int    i32x4 __attribute__((ext_vector_type(4)));
typedef int    i32x2 __attribute__((ext_vector_type(2)));

// Pack 8 f32 -> 8 fp8 e4m3 bytes via v_cvt_pk_fp8_f32.
static __device__ __forceinline__ long pack_fp8x8(const f32x8 v) {
    int lo = __builtin_amdgcn_cvt_pk_fp8_f32(v[0], v[1], 0, false);
    lo     = __builtin_amdgcn_cvt_pk_fp8_f32(v[2], v[3], lo, true);
    int hi = __builtin_amdgcn_cvt_pk_fp8_f32(v[4], v[5], 0, false);
    hi     = __builtin_amdgcn_cvt_pk_fp8_f32(v[6], v[7], hi, true);
    i32x2 r = {lo, hi};
    return __builtin_bit_cast(long, r);
}

// Prep: codebook -> fp8(-256*c) in MFMA-fragment order; c2 = 128*||c||^2+256;
// zero loss slot. Fragment byte index for (code k, dim d):
//   t=k>>4, li=k&15, kk=d>>5, hi=(d>>3)&3, j=d&7 -> ((t*2+kk)*64 + hi*16+li)*8 + j
// Scale 2^7 lifts |2c|<=1/256 out of the e4m3 subnormal floor; +256 bias keeps
// distance keys strictly positive so uint compare == float compare.
__global__ void vq_prep(const float* __restrict__ cb,
                        unsigned char* __restrict__ cbf,
                        float* __restrict__ c2,
                        float* __restrict__ out_loss) {
    const int k = blockIdx.x;
    const int d = threadIdx.x;
    const float v = cb[k * DIM + d];
    float s = v * v;
    #pragma unroll
    for (int sh = 1; sh < 64; sh <<= 1) s += __shfl_xor(s, sh, 64);
    if (d == 0) c2[k] = 128.0f * s + 256.0f;

    const int t = k >> 4, li = k & 15;
    const int kk = d >> 5, hi = (d >> 3) & 3, j = d & 7;
    const int slot = (t * 2 + kk) * 64 + hi * 16 + li;
    const int p = __builtin_amdgcn_cvt_pk_fp8_f32(-256.0f * v, 0.0f, 0, false);
    cbf[slot * 8 + j] = (unsigned char)(p & 0xFF);

    if (k == 0 && d == 0) *out_loss = 0.0f;
}

// One 32-token tile: convert -> argmin (fp8 MFMA from LDS) -> gather+write+loss.
// Flat macro, NO lambda (R12: byref f32x8 lambda captures -> alloca -> 100 MB
// scratch traffic despite VGPR=64 under a 128 cap).
#define TILE_BODY(V00, V01, V10, V11, TOK0)                                            \
    {                                                                                  \
        long af00, af01, af10, af11;                                                   \
        float z2a, z2b;                                                                \
        {                                                                              \
            float zs = 0.f;                                                            \
            _Pragma("unroll")                                                          \
            for (int j = 0; j < 8; ++j) zs += (V00)[j] * (V00)[j] + (V01)[j] * (V01)[j]; \
            af00 = pack_fp8x8(V00); af01 = pack_fp8x8(V01);                            \
            zs += __shfl_xor(zs, 16, 64); zs += __shfl_xor(zs, 32, 64);                \
            z2a = zs;                                                                  \
        }                                                                              \
        {                                                                              \
            float zs = 0.f;                                                            \
            _Pragma("unroll")                                                          \
            for (int j = 0; j < 8; ++j) zs += (V10)[j] * (V10)[j] + (V11)[j] * (V11)[j]; \
            af10 = pack_fp8x8(V10); af11 = pack_fp8x8(V11);                            \
            zs += __shfl_xor(zs, 16, 64); zs += __shfl_xor(zs, 32, 64);                \
            z2b = zs;                                                                  \
        }                                                                              \
        unsigned bkey[2][4];                                                           \
        _Pragma("unroll")                                                              \
        for (int m = 0; m < 2; ++m)                                                    \
            _Pragma("unroll")                                                          \
            for (int r = 0; r < 4; ++r) bkey[m][r] = 0xFFFFFFFFu;                      \
        _Pragma("unroll 4")                                                            \
        for (int t = 0; t < 32; ++t) {                                                 \
            const long b0 = *(const long*)&cbs[((t * 2 + 0) * 64 + lane) * 8];         \
            const long b1 = *(const long*)&cbs[((t * 2 + 1) * 64 + lane) * 8];         \
            const float cv = c2s[t * 16 + li];                                         \
            const unsigned code = (unsigned)(t * 16 + li);                             \
            _Pragma("unroll")                                                          \
            for (int m = 0; m < 2; ++m) {                                              \
                f32x4 acc = {cv, cv, cv, cv};                                          \
                acc = __builtin_amdgcn_mfma_f32_16x16x32_fp8_fp8(                      \
                          m ? af10 : af00, b0, acc, 0, 0, 0);                          \
                acc = __builtin_amdgcn_mfma_f32_16x16x32_fp8_fp8(                      \
                          m ? af11 : af01, b1, acc, 0, 0, 0);                          \
                _Pragma("unroll")                                                      \
                for (int r = 0; r < 4; ++r) {                                          \
                    const unsigned key =                                               \
                        (__builtin_bit_cast(unsigned, acc[r]) & ~511u) | code;         \
                    if (key < bkey[m][r]) bkey[m][r] = key;                            \
                }                                                                      \
            }                                                                          \
        }                                                                              \
        _Pragma("unroll")                                                              \
        for (int sh = 1; sh < 16; sh <<= 1) {                                          \
            _Pragma("unroll")                                                          \
            for (int m = 0; m < 2; ++m)                                                \
                _Pragma("unroll")                                                      \
                for (int r = 0; r < 4; ++r) {                                          \
                    const unsigned ok = (unsigned)__shfl_xor((int)bkey[m][r], sh, 64); \
                    if (ok < bkey[m][r]) bkey[m][r] = ok;                              \
                }                                                                      \
        }                                                                              \
        if (li == 0) {                                                                 \
            _Pragma("unroll")                                                          \
            for (int m = 0; m < 2; ++m)                                                \
                _Pragma("unroll")                                                      \
                for (int r = 0; r < 4; ++r)                                            \
                    keysl[wave][m * 16 + hi * 4 + r] = (int)bkey[m][r];                \
        }                                                                              \
        _Pragma("unroll")                                                              \
        for (int m = 0; m < 2; ++m) {                                                  \
            const unsigned key = (unsigned)keysl[wave][m * 16 + li];                   \
            const int code = (int)(key & 511u);                                        \
            if (hi == 0) {                                                             \
                const float kf = __builtin_bit_cast(float, key & ~511u);               \
                lossp += __builtin_fmaf(kf - 256.0f, 0.0078125f, m ? z2b : z2a);       \
            }                                                                          \
            const float* cbr = cb + code * DIM + hi * 8;                               \
            const f32x8 q0 = *(const f32x8*)(cbr);                                     \
            const f32x8 q1 = *(const f32x8*)(cbr + 32);                                \
            float* op = out + (size_t)((TOK0) + m * 16 + li) * DIM + hi * 8;           \
            __builtin_nontemporal_store(q0, (f32x8*)(op));                             \
            __builtin_nontemporal_store(q1, (f32x8*)(op + 32));                        \
        }                                                                              \
    }

// Main: 512 blocks x 512 thr (8 waves), 2 tiles/wave = 512 tokens/block.
// Tile-1 z-loads are issued BEFORE tile-0 compute and stay in flight across
// ~2500 cy of MFMA/VALU -> each wave continuously interleaves memory & compute
// instead of phase-locked bursts. fp8 codebook = 32 KiB LDS, one barrier.
// launch_bounds(512,4): 128-VGPR cap (R3/R6/R11: tighter/absent -> spill).
__global__ __launch_bounds__(512, 4) void vq_main(
    const float* __restrict__ z,
    const float* __restrict__ cb,              // fp32 codebook (exact gather)
    const unsigned char* __restrict__ cbf,     // fp8(-256c), fragment order
    const float* __restrict__ c2g,             // 128*||c||^2 + 256
    float* __restrict__ out)
{
    __shared__ unsigned char cbs[KCODES * DIM];   // 32 KiB
    __shared__ float c2s[KCODES];                 // 2 KiB
    __shared__ int   keysl[8][32];
    __shared__ float lpart[8];

    const int tid  = threadIdx.x;
    const int wave = tid >> 6;
    const int lane = tid & 63;
    const int li   = lane & 15;
    const int hi   = lane >> 4;

    const int token0 = blockIdx.x * 512 + wave * 64;   // tiles: token0, token0+32

    // ---- tile-0 z loads issue first ----
    const float* zb0 = z + (size_t)token0 * DIM + li * DIM + hi * 8;
    const f32x8 c00 = *(const f32x8*)(zb0);
    const f32x8 c01 = *(const f32x8*)(zb0 + 32);
    const f32x8 c10 = *(const f32x8*)(zb0 + 16 * DIM);
    const f32x8 c11 = *(const f32x8*)(zb0 + 16 * DIM + 32);

    // ---- stage fp8 codebook + c2 (linear, conflict-free) ----
    #pragma unroll
    for (int i = 0; i < 4; ++i)
        ((i32x4*)cbs)[i * 512 + tid] = ((const i32x4*)cbf)[i * 512 + tid];
    c2s[tid] = c2g[tid];
    __syncthreads();

    // ---- tile-1 z loads: in flight across ALL of tile-0's compute ----
    const float* zb1 = zb0 + 32 * DIM;
    const f32x8 n00 = *(const f32x8*)(zb1);
    const f32x8 n01 = *(const f32x8*)(zb1 + 32);
    const f32x8 n10 = *(const f32x8*)(zb1 + 16 * DIM);
    const f32x8 n11 = *(const f32x8*)(zb1 + 16 * DIM + 32);
    __builtin_amdgcn_sched_barrier(0);   // pin prefetch issue point

    float lossp = 0.f;
    TILE_BODY(c00, c01, c10, c11, token0);        // tile 0 (tile 1 in flight)
    TILE_BODY(n00, n01, n10, n11, token0 + 32);   // tile 1

    // ---- loss: wave shuffle -> per-wave slot -> one atomic per block ----
    #pragma unroll
    for (int sh = 1; sh < 64; sh <<= 1) lossp += __shfl_xor(lossp, sh, 64);
    if (lane == 0) lpart[wave] = lossp;
    __syncthreads();
    if (tid == 0) {
        float s = 0.f;
        #pragma unroll
        for (int w = 0; w < 8; ++w) s += lpart[w];
        atomicAdd(out + OUT_ELEMS, s * LOSS_SCALE);
    }
}

extern "C" void kernel_launch(void* const* d_in, const int* in_sizes, int n_in,
                              void* d_out, int out_size, void* d_ws, size_t ws_size,
                              hipStream_t stream) {
    const float* z  = (const float*)d_in[0];
    const float* cb = (const float*)d_in[1];
    float* out = (float*)d_out;

    unsigned char* cbf = (unsigned char*)d_ws;                       // 32 KiB
    float* c2 = (float*)((char*)d_ws + KCODES * DIM);                // 2 KiB

    vq_prep<<<KCODES, 64, 0, stream>>>(cb, cbf, c2, out + OUT_ELEMS);
    vq_main<<<N_TOKENS / 512, 512, 0, stream>>>(z, cb, cbf, c2, out);
}

// Round 15
// 37.399 us; speedup vs baseline: 1.6091x; 1.2451x over previous
//
#include <hip/hip_runtime.h>
#include <hip/hip_bf16.h>

#define N_TOKENS   262144
#define DIM        64
#define KCODES     512
#define OUT_ELEMS  (N_TOKENS * DIM)          // 16777216
#define LOSS_SCALE (1.25f / 16777216.0f)

typedef float  f32x4 __attribute__((ext_vector_type(4)));
typedef float  f32x8 __attribute__((ext_vector_type(8)));
typedef int    i32x4 __attribute__((ext_vector_type(4)));
typedef int    i32x2 __attribute__((ext_vector_type(2)));
typedef unsigned short u16x8 __attribute__((ext_vector_type(8)));

static __device__ __forceinline__ unsigned short f2bf(float f) {
    unsigned int u = __builtin_bit_cast(unsigned int, f);
    u += 0x7fffu + ((u >> 16) & 1u);          // round-to-nearest-even
    return (unsigned short)(u >> 16);
}

// Pack 8 f32 -> 8 fp8 e4m3 bytes via v_cvt_pk_fp8_f32.
static __device__ __forceinline__ long pack_fp8x8(const f32x8 v) {
    int lo = __builtin_amdgcn_cvt_pk_fp8_f32(v[0], v[1], 0, false);
    lo     = __builtin_amdgcn_cvt_pk_fp8_f32(v[2], v[3], lo, true);
    int hi = __builtin_amdgcn_cvt_pk_fp8_f32(v[4], v[5], 0, false);
    hi     = __builtin_amdgcn_cvt_pk_fp8_f32(v[6], v[7], hi, true);
    i32x2 r = {lo, hi};
    return __builtin_bit_cast(long, r);
}

// Prep: codebook -> fp8(-256*c) in MFMA-fragment order; c2 = 128*||c||^2+256;
// zero loss slot. Fragment byte index for (code k, dim d):
//   t=k>>4, li=k&15, kk=d>>5, hi=(d>>3)&3, j=d&7 -> ((t*2+kk)*64 + hi*16+li)*8 + j
// Scale 2^7 lifts |2c|<=1/256 out of the e4m3 subnormal floor; +256 bias keeps
// distance keys strictly positive so uint compare == float compare.
__global__ void vq_prep(const float* __restrict__ cb,
                        unsigned char* __restrict__ cbf,
                        float* __restrict__ c2,
                        float* __restrict__ out_loss) {
    const int k = blockIdx.x;
    const int d = threadIdx.x;
    const float v = cb[k * DIM + d];
    float s = v * v;
    #pragma unroll
    for (int sh = 1; sh < 64; sh <<= 1) s += __shfl_xor(s, sh, 64);
    if (d == 0) c2[k] = 128.0f * s + 256.0f;

    const int t = k >> 4, li = k & 15;
    const int kk = d >> 5, hi = (d >> 3) & 3, j = d & 7;
    const int slot = (t * 2 + kk) * 64 + hi * 16 + li;
    const int p = __builtin_amdgcn_cvt_pk_fp8_f32(-256.0f * v, 0.0f, 0, false);
    cbf[slot * 8 + j] = (unsigned char)(p & 0xFF);

    if (k == 0 && d == 0) *out_loss = 0.0f;
}

// Main: 256 blocks x 1024 threads (16 waves), 2x 32-token tiles per wave.
// Structure = R7 (best: 36.4us) with two changes:
//  (1) argmin codebook is fp8 fragments (32 KiB stage, half of R7's bf16);
//  (2) z_q epilogue reads a row-major bf16 codebook copy from LDS (XOR-swizzled)
//      instead of gathering fp32 rows from L2 -- removes the 64-lane divergent
//      gather (~200-400cy serial) from every tile's critical path. bf16 row
//      error <= 4e-6 vs 2.5e-2 threshold.
// PLAIN stores only: __builtin_nontemporal_store = +45 MB HBM WRITE
// (R11/R12/R14 invariant; NT bypasses L2 write-coalescing).
// launch_bounds(1024,4): 128-VGPR cap (R3/R6/R11: tighter/absent -> spill).
__global__ __launch_bounds__(1024, 4) void vq_main(
    const float* __restrict__ z,
    const float* __restrict__ cb,              // fp32 codebook
    const unsigned char* __restrict__ cbf,     // fp8(-256c), fragment order
    const float* __restrict__ c2g,             // 128*||c||^2 + 256
    float* __restrict__ out)
{
    __shared__ unsigned char cbs[KCODES * DIM];      // 32 KiB fp8 fragments
    __shared__ unsigned char cbrow[KCODES * 128];    // 64 KiB bf16 rows, swizzled
    __shared__ float c2s[KCODES];                    // 2 KiB
    __shared__ int   keysl[16][32];                  // 2 KiB
    __shared__ float lpart[16];

    const int tid  = threadIdx.x;
    const int wave = tid >> 6;
    const int lane = tid & 63;
    const int li   = lane & 15;   // A-row / C-col lane index
    const int hi   = lane >> 4;   // k-group

    // ---- stage fp8 fragment codebook (linear, conflict-free) ----
    #pragma unroll
    for (int i = 0; i < 2; ++i)
        ((i32x4*)cbs)[i * 1024 + tid] = ((const i32x4*)cbf)[i * 1024 + tid];
    if (tid < KCODES) c2s[tid] = c2g[tid];

    // ---- stage row-major bf16 codebook with XOR swizzle ----
    // thread t: row r = t>>1, dims h*32..h*32+31; slot (h*4+c) of 8 x 16B slots
    // at byte offset r*128 + ((h*64 + c*16) ^ ((r&7)<<4)).
    {
        const int r = tid >> 1, h = tid & 1;
        const float* src = cb + r * DIM + h * 32;
        const int sw = (r & 7) << 4;
        #pragma unroll
        for (int c = 0; c < 4; ++c) {
            const f32x8 v = *(const f32x8*)(src + c * 8);
            u16x8 b;
            #pragma unroll
            for (int j = 0; j < 8; ++j) b[j] = f2bf(v[j]);
            *(u16x8*)&cbrow[r * 128 + ((h * 64 + c * 16) ^ sw)] = b;
        }
    }
    __syncthreads();   // the only block-wide barrier before the loss epilogue

    float lossp = 0.f;

    #pragma unroll
    for (int tt = 0; tt < 2; ++tt) {
        const int token0 = blockIdx.x * 1024 + wave * 64 + tt * 32;

        // ---- z loads + fp8 A-fragments + exact fp32 ||z||^2 ----
        const float* zb = z + (size_t)token0 * DIM + li * DIM + hi * 8;
        const f32x8 v00 = *(const f32x8*)(zb);
        const f32x8 v01 = *(const f32x8*)(zb + 32);
        const f32x8 v10 = *(const f32x8*)(zb + 16 * DIM);
        const f32x8 v11 = *(const f32x8*)(zb + 16 * DIM + 32);

        long af[2][2];
        float z2[2];
        {
            float zs = 0.f;
            #pragma unroll
            for (int j = 0; j < 8; ++j) zs += v00[j] * v00[j] + v01[j] * v01[j];
            af[0][0] = pack_fp8x8(v00);
            af[0][1] = pack_fp8x8(v01);
            zs += __shfl_xor(zs, 16, 64);
            zs += __shfl_xor(zs, 32, 64);
            z2[0] = zs;
        }
        {
            float zs = 0.f;
            #pragma unroll
            for (int j = 0; j < 8; ++j) zs += v10[j] * v10[j] + v11[j] * v11[j];
            af[1][0] = pack_fp8x8(v10);
            af[1][1] = pack_fp8x8(v11);
            zs += __shfl_xor(zs, 16, 64);
            zs += __shfl_xor(zs, 32, 64);
            z2[1] = zs;
        }

        // ---- argmin over 512 codes; fp8 B-fragments from LDS ----
        unsigned bkey[2][4];
        #pragma unroll
        for (int m = 0; m < 2; ++m)
            #pragma unroll
            for (int r = 0; r < 4; ++r) bkey[m][r] = 0xFFFFFFFFu;

        #pragma unroll 4
        for (int t = 0; t < 32; ++t) {
            const long b0 = *(const long*)&cbs[((t * 2 + 0) * 64 + lane) * 8];
            const long b1 = *(const long*)&cbs[((t * 2 + 1) * 64 + lane) * 8];
            const float cv = c2s[t * 16 + li];
            const unsigned code = (unsigned)(t * 16 + li);
            #pragma unroll
            for (int m = 0; m < 2; ++m) {
                f32x4 acc = {cv, cv, cv, cv};
                acc = __builtin_amdgcn_mfma_f32_16x16x32_fp8_fp8(af[m][0], b0, acc, 0, 0, 0);
                acc = __builtin_amdgcn_mfma_f32_16x16x32_fp8_fp8(af[m][1], b1, acc, 0, 0, 0);
                // acc[r] = 128*(||c||^2 - 2 z.c) + 256, row m*16+hi*4+r, col code
                #pragma unroll
                for (int r = 0; r < 4; ++r) {
                    const unsigned key = (__builtin_bit_cast(unsigned, acc[r]) & ~511u) | code;
                    if (key < bkey[m][r]) bkey[m][r] = key;   // v_and_or + v_min_u32
                }
            }
        }

        // ---- reduce across the 16 li-lanes (positive keys: uint min) ----
        #pragma unroll
        for (int sh = 1; sh < 16; sh <<= 1) {
            #pragma unroll
            for (int m = 0; m < 2; ++m)
                #pragma unroll
                for (int r = 0; r < 4; ++r) {
                    const unsigned ok = (unsigned)__shfl_xor((int)bkey[m][r], sh, 64);
                    if (ok < bkey[m][r]) bkey[m][r] = ok;
                }
        }

        // rows m*16 + hi*4 + r -> key; wave-private slab (same-wave DS ordered)
        if (li == 0) {
            #pragma unroll
            for (int m = 0; m < 2; ++m)
                #pragma unroll
                for (int r = 0; r < 4; ++r)
                    keysl[wave][m * 16 + hi * 4 + r] = (int)bkey[m][r];
        }

        // ---- epilogue: z_q row from LDS bf16 (swizzled), plain stores ----
        #pragma unroll
        for (int m = 0; m < 2; ++m) {
            const unsigned key = (unsigned)keysl[wave][m * 16 + li];  // row = m*16+li
            const int code = (int)(key & 511u);
            if (hi == 0) {
                const float kf = __builtin_bit_cast(float, key & ~511u);
                lossp += __builtin_fmaf(kf - 256.0f, 0.0078125f, z2[m]);
            }
            const int rb = code * 128, sw = (code & 7) << 4;
            const u16x8 h0 = *(const u16x8*)&cbrow[rb + ((hi * 16) ^ sw)];
            const u16x8 h1 = *(const u16x8*)&cbrow[rb + ((64 + hi * 16) ^ sw)];
            f32x8 q0, q1;
            #pragma unroll
            for (int j = 0; j < 8; ++j) {
                q0[j] = __builtin_bit_cast(float, (unsigned)h0[j] << 16);
                q1[j] = __builtin_bit_cast(float, (unsigned)h1[j] << 16);
            }
            float* op = out + (size_t)(token0 + m * 16 + li) * DIM + hi * 8;
            *(f32x8*)(op)      = q0;
            *(f32x8*)(op + 32) = q1;
        }
    }

    // ---- loss: wave shuffle -> per-wave slot -> one atomic per block ----
    #pragma unroll
    for (int sh = 1; sh < 64; sh <<= 1) lossp += __shfl_xor(lossp, sh, 64);
    if (lane == 0) lpart[wave] = lossp;
    __syncthreads();
    if (tid == 0) {
        float s = 0.f;
        #pragma unroll
        for (int w = 0; w < 16; ++w) s += lpart[w];
        atomicAdd(out + OUT_ELEMS, s * LOSS_SCALE);
    }
}

extern "C" void kernel_launch(void* const* d_in, const int* in_sizes, int n_in,
                              void* d_out, int out_size, void* d_ws, size_t ws_size,
                              hipStream_t stream) {
    const float* z  = (const float*)d_in[0];
    const float* cb = (const float*)d_in[1];
    float* out = (float*)d_out;

    unsigned char* cbf = (unsigned char*)d_ws;                       // 32 KiB
    float* c2 = (float*)((char*)d_ws + KCODES * DIM);                // 2 KiB

    vq_prep<<<KCODES, 64, 0, stream>>>(cb, cbf, c2, out + OUT_ELEMS);
    vq_main<<<N_TOKENS / 1024, 1024, 0, stream>>>(z, cb, cbf, c2, out);
}